// Round 7
// baseline (158.517 us; speedup 1.0000x reference)
//
#include <hip/hip_runtime.h>
#include <hip/hip_bf16.h>
#include <stdint.h>

// LePEAttention, chained-MFMA v2: keys-outer / 8 parallel query-chains.
// B=4, C=64, H=W=128, heads=8, hd=8, window=128x2 (256 toks).
// Grid 512 = (b, wj, hf, x); block = 512 thr = 8 waves; wave = (head=w>>1, qhalf=w&1).
// Per key-pair-tile (32 keys): 2 QK mfma_16x16x32 (A=K,B=Q -> S^T) per qg,
// exp -> pack -> ONE PV mfma_16x16x32 whose (quad,j) k-slots are permuted keys,
// identical permutation on A (=V^T) side. 8 independent acc chains hide latency.

typedef __attribute__((ext_vector_type(8))) short bf16x8;
typedef __attribute__((ext_vector_type(4))) float f32x4;

static __device__ __forceinline__ uint32_t pk2(float x, float y) {
    union { __hip_bfloat162 h2; uint32_t u; } c;
    c.h2 = __float22bfloat162_rn(make_float2(x, y));
    return c.u;
}
static __device__ __forceinline__ float bflo(uint32_t u){ return __uint_as_float(u<<16); }
static __device__ __forceinline__ float bfhi(uint32_t u){ return __uint_as_float(u & 0xffff0000u); }

__global__ __launch_bounds__(512, 4)
void lepe_attn(const float* __restrict__ temp,
               const float* __restrict__ conv_w,
               const float* __restrict__ conv_b,
               float* __restrict__ out)
{
    __shared__ __align__(16) char smem[73728];
    char* q_s = smem;                 // [256 tok][72B] scaled-Q bf16 (32 ch)
    char* k_s = smem + 18432;         // [256 tok][72B] K bf16
    char* r_s = smem + 36864;         // [256 tok][72B] rpe bf16
    char* v_t = smem + 55296;         // [32 ch][536B]: tok t at byte 8+2t; zeros at 4..7 / 520..523
    float* cw_s = (float*)(smem + 72448);  // 288 conv w + 32 bias

    const int tid  = threadIdx.x;
    const int wave = tid >> 6, lane = tid & 63;
    const int lr = lane & 15, quad = lane >> 4;
    const int head = wave >> 1, qbase = (wave & 1) * 8;

    // bid = ((b*8 + wj)*2 + hf)*8 + x : XCD = x owns a wi-octet.
    const int bid = blockIdx.x;
    const int x  = bid & 7;
    int t_ = bid >> 3;
    const int hf = t_ & 1;  t_ >>= 1;
    const int wj = t_ & 7;
    const int b  = t_ >> 3;
    const int wi = x * 8 + wj;
    const int c0 = hf * 32;

    const size_t cstr = 16384, sstr = 64 * cstr;
    const float qs = 0.35355339059327373f * 1.4426950408889634f;  // hd^-0.5 * log2e

    // ---- staging: thread (cg = ch 0..31, hh0 = row-group 0..15) ----
    {
        const int cg = tid & 31, hh0 = tid >> 5;
        const float* qp = temp + (size_t)b*3*sstr + (size_t)(c0+cg)*cstr + wi*2;
        #pragma unroll
        for (int i = 0; i < 8; ++i) {
            int h = i*16 + hh0;
            float2 fq = *(const float2*)(qp + (size_t)h*128);
            uint32_t uq = pk2(fq.x*qs, fq.y*qs);
            *(uint16_t*)(q_s + (2*h)*72   + cg*2) = (uint16_t)uq;
            *(uint16_t*)(q_s + (2*h+1)*72 + cg*2) = (uint16_t)(uq>>16);
            float2 fk = *(const float2*)(qp + sstr + (size_t)h*128);
            uint32_t uk = pk2(fk.x, fk.y);
            *(uint16_t*)(k_s + (2*h)*72   + cg*2) = (uint16_t)uk;
            *(uint16_t*)(k_s + (2*h+1)*72 + cg*2) = (uint16_t)(uk>>16);
            float2 fv = *(const float2*)(qp + 2*sstr + (size_t)h*128);
            *(uint32_t*)(v_t + cg*536 + 8 + 4*h) = pk2(fv.x, fv.y);
        }
        if (tid < 288) cw_s[tid] = conv_w[c0*9 + tid];
        if (tid < 32) {
            cw_s[288 + tid] = conv_b[c0 + tid];
            *(uint32_t*)(v_t + tid*536 + 4)   = 0;   // toks -2,-1
            *(uint32_t*)(v_t + tid*536 + 520) = 0;   // toks 256,257
        }
    }
    __syncthreads();

    // ---- Q B-frags for this wave's 8 query-groups ----
    const uint4 z4 = make_uint4(0,0,0,0);
    uint4 qf[8];
    #pragma unroll
    for (int g = 0; g < 8; ++g) {
        uint4 t = *(const uint4*)(q_s + ((qbase+g)*16 + lr)*72 + head*16);
        qf[g] = (lane < 16) ? t : z4;
    }

    // ---- rpe = depthwise 3x3 conv of V (window-local) -> r_s bf16 ----
    {
        const int ch = tid & 31, seg = tid >> 5;     // 16 toks per thread
        const char* base = v_t + ch*536 + seg*32;
        uint32_t d[12];
        #pragma unroll
        for (int i = 0; i < 6; ++i) *(uint2*)(d + 2*i) = *(const uint2*)(base + 8*i);
        float w9[9];
        #pragma unroll
        for (int k = 0; k < 9; ++k) w9[k] = cw_s[ch*9 + k];
        const float bia = cw_s[288 + ch];
        #pragma unroll
        for (int tt = 0; tt < 16; ++tt) {
            int tok = seg*16 + tt;
            int w01 = tt & 1;
            int L = (tt >> 1)*2 + 2;      // bf16 idx = L + 2dy + wp
            float rp = bia;
            #pragma unroll
            for (int dy = 0; dy < 3; ++dy) {
                #pragma unroll
                for (int wp = 0; wp < 2; ++wp) {
                    int idx = L + 2*dy + wp;
                    uint32_t dw = d[idx >> 1];
                    rp = fmaf(w9[dy*3 + wp + 1 - w01], (idx&1) ? bfhi(dw) : bflo(dw), rp);
                }
            }
            union { __hip_bfloat16 h; uint16_t u; } cv;
            cv.h = __float2bfloat16(rp);
            *(uint16_t*)(r_s + tok*72 + ch*2) = cv.u;
        }
    }
    __syncthreads();

    // ---- main: 8 key-pair tiles x 8 query-groups, 8 independent acc chains ----
    const f32x4 zf = {0.f, 0.f, 0.f, 0.f};
    f32x4 acc[8];
    float rsum[8];
    #pragma unroll
    for (int g = 0; g < 8; ++g) { acc[g] = zf; rsum[g] = 0.f; }

    const char* kbase = k_s + lr*72 + head*16;
    const char* vbase = v_t + (head*8 + (lane&7))*536 + 8 + quad*8;

    #pragma unroll 2
    for (int T = 0; T < 8; ++T) {
        uint4 ka = *(const uint4*)(kbase + (T*32)*72);
        uint4 kb = *(const uint4*)(kbase + (T*32+16)*72);
        union { uint4 u; bf16x8 h; } kfa, kfb;
        kfa.u = (lane < 16) ? ka : z4;
        kfb.u = (lane < 16) ? kb : z4;
        uint2 vlo = *(const uint2*)(vbase + T*64);        // keys 32T+quad*4+0..3
        uint2 vhi = *(const uint2*)(vbase + T*64 + 32);   // keys 32T+16+quad*4+0..3
        union { uint4 u; bf16x8 h; } vf;
        vf.u = (lr < 8) ? make_uint4(vlo.x, vlo.y, vhi.x, vhi.y) : z4;
        #pragma unroll
        for (int g = 0; g < 8; ++g) {
            union { uint4 u; bf16x8 h; } qa; qa.u = qf[g];
            f32x4 sa = __builtin_amdgcn_mfma_f32_16x16x32_bf16(kfa.h, qa.h, zf, 0, 0, 0);
            f32x4 sb = __builtin_amdgcn_mfma_f32_16x16x32_bf16(kfb.h, qa.h, zf, 0, 0, 0);
            float e0 = __builtin_amdgcn_exp2f(sa[0]);
            float e1 = __builtin_amdgcn_exp2f(sa[1]);
            float e2 = __builtin_amdgcn_exp2f(sa[2]);
            float e3 = __builtin_amdgcn_exp2f(sa[3]);
            float f0 = __builtin_amdgcn_exp2f(sb[0]);
            float f1 = __builtin_amdgcn_exp2f(sb[1]);
            float f2 = __builtin_amdgcn_exp2f(sb[2]);
            float f3 = __builtin_amdgcn_exp2f(sb[3]);
            rsum[g] += ((e0+e1)+(e2+e3)) + ((f0+f1)+(f2+f3));
            union { uint4 u; bf16x8 h; } pb;
            pb.u = make_uint4(pk2(e0,e1), pk2(e2,e3), pk2(f0,f1), pk2(f2,f3));
            acc[g] = __builtin_amdgcn_mfma_f32_16x16x32_bf16(vf.h, pb.h, acc[g], 0, 0, 0);
        }
    }

    // ---- epilogue: normalize + rpe + store (quads 0,1 hold d=0..7) ----
    #pragma unroll
    for (int g = 0; g < 8; ++g) {
        float rs = rsum[g];
        rs += __shfl_xor(rs, 16);
        rs += __shfl_xor(rs, 32);
        const float rinv = 1.0f / rs;
        if (quad < 2) {
            int tok = (qbase + g)*16 + lr;
            int h = tok >> 1, w01 = tok & 1;
            uint2 rp2 = *(const uint2*)(r_s + tok*72 + (head*8 + quad*4)*2);
            float4 ov;
            ov.x = fmaf(acc[g][0], rinv, bflo(rp2.x));
            ov.y = fmaf(acc[g][1], rinv, bfhi(rp2.x));
            ov.z = fmaf(acc[g][2], rinv, bflo(rp2.y));
            ov.w = fmaf(acc[g][3], rinv, bfhi(rp2.y));
            size_t addr = (size_t)b*1048576 + (size_t)(h*128 + wi*2 + w01)*64
                        + c0 + head*8 + quad*4;
            *(float4*)(out + addr) = ov;
        }
    }
}

extern "C" void kernel_launch(void* const* d_in, const int* in_sizes, int n_in,
                              void* d_out, int out_size, void* d_ws, size_t ws_size,
                              hipStream_t stream) {
    const float* temp = (const float*)d_in[0];
    const float* cw   = (const float*)d_in[1];
    const float* cb   = (const float*)d_in[2];
    float* o = (float*)d_out;
    (void)in_sizes; (void)n_in; (void)out_size; (void)d_ws; (void)ws_size;
    lepe_attn<<<dim3(512), dim3(512), 0, stream>>>(temp, cw, cb, o);
}

// Round 8
// 132.807 us; speedup vs baseline: 1.1936x; 1.1936x over previous
//
#include <hip/hip_runtime.h>
#include <hip/hip_bf16.h>
#include <stdint.h>

// LePEAttention, chained-MFMA v3: keys-outer, 2 passes x 4 parallel query-chains.
// B=4, C=64, H=W=128, heads=8, hd=8, window=128x2 (256 toks).
// Grid 512 = (b, wj, hf, x); block = 512 thr = 8 waves; wave = (head=w>>1, qhalf=w&1).
// Per key-pair-tile (32 keys): 2 QK mfma_16x16x32 (A=K,B=Q -> S^T) per qg,
// exp -> pack -> ONE PV mfma_16x16x32 with (quad,j)<->key slot permutation applied
// identically on A (=V^T) side. 4 chains/wave x 4 waves/SIMD hide chain latency.
// v3 fix vs r7: launch_bounds(512,2) + 4-chain passes -> no VGPR spill (r7: cap 64, spilled).

typedef __attribute__((ext_vector_type(8))) short bf16x8;
typedef __attribute__((ext_vector_type(4))) float f32x4;

static __device__ __forceinline__ uint32_t pk2(float x, float y) {
    union { __hip_bfloat162 h2; uint32_t u; } c;
    c.h2 = __float22bfloat162_rn(make_float2(x, y));
    return c.u;
}
static __device__ __forceinline__ float bflo(uint32_t u){ return __uint_as_float(u<<16); }
static __device__ __forceinline__ float bfhi(uint32_t u){ return __uint_as_float(u & 0xffff0000u); }

__global__ __launch_bounds__(512, 2)
void lepe_attn(const float* __restrict__ temp,
               const float* __restrict__ conv_w,
               const float* __restrict__ conv_b,
               float* __restrict__ out)
{
    __shared__ __align__(16) char smem[73728];
    char* q_s = smem;                 // [256 tok][72B] scaled-Q bf16 (32 ch)
    char* k_s = smem + 18432;         // [256 tok][72B] K bf16
    char* r_s = smem + 36864;         // [256 tok][72B] rpe bf16
    char* v_t = smem + 55296;         // [32 ch][536B]: tok t at byte 8+2t; zeros at 4..7 / 520..523
    float* cw_s = (float*)(smem + 72448);  // 288 conv w + 32 bias

    const int tid  = threadIdx.x;
    const int wave = tid >> 6, lane = tid & 63;
    const int lr = lane & 15, quad = lane >> 4;
    const int head = wave >> 1, qbase = (wave & 1) * 8;

    // bid = ((b*8 + wj)*2 + hf)*8 + x : XCD = x owns a wi-octet.
    const int bid = blockIdx.x;
    const int x  = bid & 7;
    int t_ = bid >> 3;
    const int hf = t_ & 1;  t_ >>= 1;
    const int wj = t_ & 7;
    const int b  = t_ >> 3;
    const int wi = x * 8 + wj;
    const int c0 = hf * 32;

    const size_t cstr = 16384, sstr = 64 * cstr;
    const float qs = 0.35355339059327373f * 1.4426950408889634f;  // hd^-0.5 * log2e

    // ---- staging: thread (cg = ch 0..31, hh0 = row-group 0..15) ----
    {
        const int cg = tid & 31, hh0 = tid >> 5;
        const float* qp = temp + (size_t)b*3*sstr + (size_t)(c0+cg)*cstr + wi*2;
        #pragma unroll
        for (int i = 0; i < 8; ++i) {
            int h = i*16 + hh0;
            float2 fq = *(const float2*)(qp + (size_t)h*128);
            uint32_t uq = pk2(fq.x*qs, fq.y*qs);
            *(uint16_t*)(q_s + (2*h)*72   + cg*2) = (uint16_t)uq;
            *(uint16_t*)(q_s + (2*h+1)*72 + cg*2) = (uint16_t)(uq>>16);
            float2 fk = *(const float2*)(qp + sstr + (size_t)h*128);
            uint32_t uk = pk2(fk.x, fk.y);
            *(uint16_t*)(k_s + (2*h)*72   + cg*2) = (uint16_t)uk;
            *(uint16_t*)(k_s + (2*h+1)*72 + cg*2) = (uint16_t)(uk>>16);
            float2 fv = *(const float2*)(qp + 2*sstr + (size_t)h*128);
            *(uint32_t*)(v_t + cg*536 + 8 + 4*h) = pk2(fv.x, fv.y);
        }
        if (tid < 288) cw_s[tid] = conv_w[c0*9 + tid];
        if (tid < 32) {
            cw_s[288 + tid] = conv_b[c0 + tid];
            *(uint32_t*)(v_t + tid*536 + 4)   = 0;   // toks -2,-1
            *(uint32_t*)(v_t + tid*536 + 520) = 0;   // toks 256,257
        }
    }
    __syncthreads();

    // ---- rpe = depthwise 3x3 conv of V (window-local) -> r_s bf16 ----
    {
        const int ch = tid & 31, seg = tid >> 5;     // 16 toks per thread
        const char* base = v_t + ch*536 + seg*32;
        uint32_t d[12];
        #pragma unroll
        for (int i = 0; i < 6; ++i) *(uint2*)(d + 2*i) = *(const uint2*)(base + 8*i);
        float w9[9];
        #pragma unroll
        for (int k = 0; k < 9; ++k) w9[k] = cw_s[ch*9 + k];
        const float bia = cw_s[288 + ch];
        #pragma unroll
        for (int tt = 0; tt < 16; ++tt) {
            int tok = seg*16 + tt;
            int w01 = tt & 1;
            int L = (tt >> 1)*2 + 2;      // bf16 idx = L + 2dy + wp
            float rp = bia;
            #pragma unroll
            for (int dy = 0; dy < 3; ++dy) {
                #pragma unroll
                for (int wp = 0; wp < 2; ++wp) {
                    int idx = L + 2*dy + wp;
                    uint32_t dw = d[idx >> 1];
                    rp = fmaf(w9[dy*3 + wp + 1 - w01], (idx&1) ? bfhi(dw) : bflo(dw), rp);
                }
            }
            union { __hip_bfloat16 h; uint16_t u; } cv;
            cv.h = __float2bfloat16(rp);
            *(uint16_t*)(r_s + tok*72 + ch*2) = cv.u;
        }
    }
    __syncthreads();

    // ---- main: 2 passes x (8 key-pair tiles x 4 query-chains) ----
    const uint4 z4 = make_uint4(0,0,0,0);
    const f32x4 zf = {0.f, 0.f, 0.f, 0.f};
    const char* kbase = k_s + lr*72 + head*16;
    const char* vbase = v_t + (head*8 + (lane&7))*536 + 8 + quad*8;

    #pragma unroll 1
    for (int p = 0; p < 2; ++p) {
        const int qg0 = qbase + p*4;
        uint4 qf[4];
        #pragma unroll
        for (int g = 0; g < 4; ++g) {
            uint4 t = *(const uint4*)(q_s + ((qg0+g)*16 + lr)*72 + head*16);
            qf[g] = (lane < 16) ? t : z4;
        }
        f32x4 acc[4];
        float rsum[4];
        #pragma unroll
        for (int g = 0; g < 4; ++g) { acc[g] = zf; rsum[g] = 0.f; }

        #pragma unroll 2
        for (int T = 0; T < 8; ++T) {
            uint4 ka = *(const uint4*)(kbase + (T*32)*72);
            uint4 kb = *(const uint4*)(kbase + (T*32+16)*72);
            union { uint4 u; bf16x8 h; } kfa, kfb;
            kfa.u = (lane < 16) ? ka : z4;
            kfb.u = (lane < 16) ? kb : z4;
            uint2 vlo = *(const uint2*)(vbase + T*64);        // keys 32T+quad*4+0..3
            uint2 vhi = *(const uint2*)(vbase + T*64 + 32);   // keys 32T+16+quad*4+0..3
            union { uint4 u; bf16x8 h; } vf;
            vf.u = (lr < 8) ? make_uint4(vlo.x, vlo.y, vhi.x, vhi.y) : z4;
            #pragma unroll
            for (int g = 0; g < 4; ++g) {
                union { uint4 u; bf16x8 h; } qa; qa.u = qf[g];
                f32x4 sa = __builtin_amdgcn_mfma_f32_16x16x32_bf16(kfa.h, qa.h, zf, 0, 0, 0);
                f32x4 sb = __builtin_amdgcn_mfma_f32_16x16x32_bf16(kfb.h, qa.h, zf, 0, 0, 0);
                float e0 = __builtin_amdgcn_exp2f(sa[0]);
                float e1 = __builtin_amdgcn_exp2f(sa[1]);
                float e2 = __builtin_amdgcn_exp2f(sa[2]);
                float e3 = __builtin_amdgcn_exp2f(sa[3]);
                float f0 = __builtin_amdgcn_exp2f(sb[0]);
                float f1 = __builtin_amdgcn_exp2f(sb[1]);
                float f2 = __builtin_amdgcn_exp2f(sb[2]);
                float f3 = __builtin_amdgcn_exp2f(sb[3]);
                rsum[g] += ((e0+e1)+(e2+e3)) + ((f0+f1)+(f2+f3));
                union { uint4 u; bf16x8 h; } pb;
                pb.u = make_uint4(pk2(e0,e1), pk2(e2,e3), pk2(f0,f1), pk2(f2,f3));
                acc[g] = __builtin_amdgcn_mfma_f32_16x16x32_bf16(vf.h, pb.h, acc[g], 0, 0, 0);
            }
        }

        // ---- pass epilogue: normalize + rpe + store (quads 0,1 hold d=0..7) ----
        #pragma unroll
        for (int g = 0; g < 4; ++g) {
            float rs = rsum[g];
            rs += __shfl_xor(rs, 16);
            rs += __shfl_xor(rs, 32);
            const float rinv = 1.0f / rs;
            if (quad < 2) {
                int tok = (qg0 + g)*16 + lr;
                int h = tok >> 1, w01 = tok & 1;
                uint2 rp2 = *(const uint2*)(r_s + tok*72 + (head*8 + quad*4)*2);
                float4 ov;
                ov.x = fmaf(acc[g][0], rinv, bflo(rp2.x));
                ov.y = fmaf(acc[g][1], rinv, bfhi(rp2.x));
                ov.z = fmaf(acc[g][2], rinv, bflo(rp2.y));
                ov.w = fmaf(acc[g][3], rinv, bfhi(rp2.y));
                size_t addr = (size_t)b*1048576 + (size_t)(h*128 + wi*2 + w01)*64
                            + c0 + head*8 + quad*4;
                *(float4*)(out + addr) = ov;
            }
        }
    }
}

extern "C" void kernel_launch(void* const* d_in, const int* in_sizes, int n_in,
                              void* d_out, int out_size, void* d_ws, size_t ws_size,
                              hipStream_t stream) {
    const float* temp = (const float*)d_in[0];
    const float* cw   = (const float*)d_in[1];
    const float* cb   = (const float*)d_in[2];
    float* o = (float*)d_out;
    (void)in_sizes; (void)n_in; (void)out_size; (void)d_ws; (void)ws_size;
    lepe_attn<<<dim3(512), dim3(512), 0, stream>>>(temp, cw, cb, o);
}